// Round 1
// 11958.271 us; speedup vs baseline: 1.2608x; 1.2608x over previous
//
#include <hip/hip_runtime.h>
#include <math.h>

#define B_  256
#define T_  512
#define D_  256
#define H_  1024
#define O_  128
#define N4H 4096          // 4*H

typedef __attribute__((ext_vector_type(8))) short bf16x8;
typedef __attribute__((ext_vector_type(4))) float f32x4;

__device__ __forceinline__ unsigned short f2bf(float x) {
    union { float f; unsigned u; } v; v.f = x;
    unsigned r = v.u + 0x7fffu + ((v.u >> 16) & 1u);
    return (unsigned short)(r >> 16);
}
__device__ __forceinline__ float bf2f(unsigned short b) {
    union { float f; unsigned u; } v; v.u = ((unsigned)b) << 16;
    return v.f;
}
// cheap split: hi = truncated top-16, lo = rne(w - hi).  hi+lo represents w
// to ~2^-17 rel regardless of hi rounding mode (lo absorbs the remainder).
__device__ __forceinline__ void splitf(float w, short& hi, short& lo) {
    union { float f; unsigned u; } v; v.f = w;
    union { float f; unsigned u; } hf; hf.u = v.u & 0xffff0000u;
    hi = (short)(unsigned short)(v.u >> 16);
    lo = (short)f2bf(w - hf.f);
}

// ---------------------------------------------------------------------------
// Pack weights, gate-interleaved rows n' = 4*j + gate (0=g,1=i,2=f,3=o):
//   Whhi/Whlo : [4096][1024]  recurrent part (hi/lo bf16)
//   WXhi/WXlo : [4096][256]   input part     (hi/lo bf16)
//   biasP     : [4096]        x-side bias (folded into xz later)
// ---------------------------------------------------------------------------
__global__ __launch_bounds__(256) void pack_weights(
    const float* __restrict__ Wgx, const float* __restrict__ bgx, const float* __restrict__ Wgh,
    const float* __restrict__ Wix, const float* __restrict__ bix, const float* __restrict__ Wih,
    const float* __restrict__ Wfx, const float* __restrict__ bfx, const float* __restrict__ Wfh,
    const float* __restrict__ Wox, const float* __restrict__ box, const float* __restrict__ Woh,
    unsigned short* __restrict__ Whhi, unsigned short* __restrict__ Whlo,
    unsigned short* __restrict__ WXhi, unsigned short* __restrict__ WXlo,
    float* __restrict__ biasP)
{
    int idx = blockIdx.x * 256 + threadIdx.x;
    const int K = H_ + D_;
    const int total = N4H * K;
    if (idx < total) {
        int np = idx / K;
        int k  = idx - np * K;
        int j = np >> 2, g = np & 3;
        const float* Wh = (g == 0) ? Wgh : (g == 1) ? Wih : (g == 2) ? Wfh : Woh;
        const float* Wx = (g == 0) ? Wgx : (g == 1) ? Wix : (g == 2) ? Wfx : Wox;
        float w = (k < H_) ? Wh[j * H_ + k] : Wx[j * D_ + (k - H_)];
        unsigned short hi = f2bf(w);
        unsigned short lo = f2bf(w - bf2f(hi));
        if (k < H_) { Whhi[np * H_ + k] = hi; Whlo[np * H_ + k] = lo; }
        else        { WXhi[np * D_ + (k - H_)] = hi; WXlo[np * D_ + (k - H_)] = lo; }
    }
    if (idx < N4H) {
        int j = idx >> 2, g = idx & 3;
        const float* bx = (g == 0) ? bgx : (g == 1) ? bix : (g == 2) ? bfx : box;
        biasP[idx] = bx[j];
    }
}

// ---------------------------------------------------------------------------
// xz precompute for a chunk of time steps:
//   xz[t_rel][b][n'] = biasP[n'] + sum_d x[b][t0+t_rel][d] * Wx[n'][d]
// Grid (32, 2*tc), block 256 (4 waves as 2x2), tile 128 rows x 128 cols,
// K=256 full per wave, 3-pass split MFMA, x split on the fly.
// ---------------------------------------------------------------------------
__global__ __launch_bounds__(256, 2) void xz_gemm(
    const float* __restrict__ x,
    const unsigned short* __restrict__ WXhi, const unsigned short* __restrict__ WXlo,
    const float* __restrict__ biasP,
    float* __restrict__ xz, int t0)
{
    const int tid  = threadIdx.x;
    const int wave = tid >> 6;
    const int lane = tid & 63;
    const int lrow = lane & 15;
    const int quad = lane >> 4;
    const int wr = wave >> 1, wc = wave & 1;

    const int cg    = blockIdx.x;       // 0..31  (128 cols each)
    const int t_rel = blockIdx.y >> 1;
    const int bhalf = blockIdx.y & 1;
    const int t     = t0 + t_rel;

    const int b0 = bhalf * 128 + wr * 64;
    const int n0 = cg * 128 + wc * 64;

    f32x4 acc[4][4];
    #pragma unroll
    for (int rs = 0; rs < 4; ++rs)
        #pragma unroll
        for (int cs = 0; cs < 4; ++cs)
            acc[rs][cs] = (f32x4){0.f, 0.f, 0.f, 0.f};

    #pragma unroll 1
    for (int kc = 0; kc < D_; kc += 32) {
        bf16x8 Ahi[4], Alo[4], Bh[4], Bl[4];
        #pragma unroll
        for (int rs = 0; rs < 4; ++rs) {
            int b = b0 + rs * 16 + lrow;
            const float* p = x + (size_t)b * (T_ * D_) + (size_t)t * D_ + kc + quad * 8;
            float4 v0 = *(const float4*)p;
            float4 v1 = *(const float4*)(p + 4);
            float vv[8] = {v0.x, v0.y, v0.z, v0.w, v1.x, v1.y, v1.z, v1.w};
            #pragma unroll
            for (int j = 0; j < 8; ++j) {
                short hi, lo; splitf(vv[j], hi, lo);
                Ahi[rs][j] = hi; Alo[rs][j] = lo;
            }
        }
        #pragma unroll
        for (int cs = 0; cs < 4; ++cs) {
            int rw = n0 + cs * 16 + lrow;
            int off = rw * D_ + kc + quad * 8;
            Bh[cs] = *(const bf16x8*)(WXhi + off);
            Bl[cs] = *(const bf16x8*)(WXlo + off);
        }
        #pragma unroll
        for (int rs = 0; rs < 4; ++rs)
            #pragma unroll
            for (int cs = 0; cs < 4; ++cs) {
                acc[rs][cs] = __builtin_amdgcn_mfma_f32_16x16x32_bf16(Ahi[rs], Bh[cs], acc[rs][cs], 0, 0, 0);
                acc[rs][cs] = __builtin_amdgcn_mfma_f32_16x16x32_bf16(Ahi[rs], Bl[cs], acc[rs][cs], 0, 0, 0);
                acc[rs][cs] = __builtin_amdgcn_mfma_f32_16x16x32_bf16(Alo[rs], Bh[cs], acc[rs][cs], 0, 0, 0);
            }
    }

    // epilogue: C/D layout col=lane&15, row=quad*4+reg
    #pragma unroll
    for (int cs = 0; cs < 4; ++cs) {
        int col = n0 + cs * 16 + lrow;
        float bv = biasP[col];
        #pragma unroll
        for (int rs = 0; rs < 4; ++rs) {
            int row0 = b0 + rs * 16 + quad * 4;
            #pragma unroll
            for (int r = 0; r < 4; ++r)
                xz[(size_t)(t_rel * B_ + row0 + r) * N4H + col] = acc[rs][cs][r] + bv;
        }
    }
}

// ---------------------------------------------------------------------------
// One LSTM time step: pure recurrent GEMM (K=1024) + epilogue (adds xz).
// Grid 256 blocks (XCD-swizzled: 8 xcd x 8 cg x 4 rg), 512 threads = 8 waves.
// Block tile 64 batch rows x 64 packed cols; waves split K 8-ways (128 each).
// LDS reduce of the 8 partials, then cell update.
// Weights per XCD = 8 cg * 64 cols * 1024 * 4B = 2.1 MB -> L2-resident.
// ---------------------------------------------------------------------------
__global__ __launch_bounds__(512, 2) void lstm_step(
    const unsigned short* __restrict__ Whhi, const unsigned short* __restrict__ Whlo,
    const unsigned short* __restrict__ hin_hi, const unsigned short* __restrict__ hin_lo,
    unsigned short* __restrict__ hout_hi, unsigned short* __restrict__ hout_lo,
    float* __restrict__ cst, const float* __restrict__ xz, int t_rel)
{
    __shared__ __align__(16) float zbuf[8][64][68];   // 139 KB

    const int tid  = threadIdx.x;
    const int wave = tid >> 6;          // 0..7, K-split
    const int lane = tid & 63;
    const int lrow = lane & 15;
    const int quad = lane >> 4;

    // XCD swizzle: consecutive fid round-robin XCDs; give each XCD 8 cgs x 4 rgs
    const int fid = blockIdx.x;
    const int xcd = fid & 7;
    const int s   = fid >> 3;           // 0..31
    const int cg  = xcd * 8 + (s & 7);  // 0..63
    const int rg  = s >> 3;             // 0..3
    const int rbase = rg * 64;
    const int cbase = cg * 64;

    f32x4 acc[4][4];
    #pragma unroll
    for (int rs = 0; rs < 4; ++rs)
        #pragma unroll
        for (int cs = 0; cs < 4; ++cs)
            acc[rs][cs] = (f32x4){0.f, 0.f, 0.f, 0.f};

    const int kb = wave * 128;
    #pragma unroll 2
    for (int kc = 0; kc < 128; kc += 32) {
        const int k = kb + kc + quad * 8;
        bf16x8 Ahi[4], Alo[4], Bh[4], Bl[4];
        #pragma unroll
        for (int rs = 0; rs < 4; ++rs) {
            int off = (rbase + rs * 16 + lrow) * H_ + k;
            Ahi[rs] = *(const bf16x8*)(hin_hi + off);
            Alo[rs] = *(const bf16x8*)(hin_lo + off);
        }
        #pragma unroll
        for (int cs = 0; cs < 4; ++cs) {
            int off = (cbase + cs * 16 + lrow) * H_ + k;
            Bh[cs] = *(const bf16x8*)(Whhi + off);
            Bl[cs] = *(const bf16x8*)(Whlo + off);
        }
        #pragma unroll
        for (int rs = 0; rs < 4; ++rs)
            #pragma unroll
            for (int cs = 0; cs < 4; ++cs) {
                acc[rs][cs] = __builtin_amdgcn_mfma_f32_16x16x32_bf16(Ahi[rs], Bh[cs], acc[rs][cs], 0, 0, 0);
                acc[rs][cs] = __builtin_amdgcn_mfma_f32_16x16x32_bf16(Ahi[rs], Bl[cs], acc[rs][cs], 0, 0, 0);
                acc[rs][cs] = __builtin_amdgcn_mfma_f32_16x16x32_bf16(Alo[rs], Bh[cs], acc[rs][cs], 0, 0, 0);
            }
    }

    // per-wave partials to LDS
    #pragma unroll
    for (int rs = 0; rs < 4; ++rs)
        #pragma unroll
        for (int cs = 0; cs < 4; ++cs)
            #pragma unroll
            for (int r = 0; r < 4; ++r)
                zbuf[wave][rs * 16 + quad * 4 + r][cs * 16 + lrow] = acc[rs][cs][r];
    __syncthreads();

    // epilogue: 512 threads x 8 z-values = 2 LSTM cells each
    const int b_loc = tid >> 3;          // 0..63
    const int oc    = (tid & 7) * 8;     // 0..56

    float zz[8];
    #pragma unroll
    for (int i = 0; i < 8; i += 4) {
        float s0 = 0.f, s1 = 0.f, s2 = 0.f, s3 = 0.f;
        #pragma unroll
        for (int w = 0; w < 8; ++w) {
            float4 v = *(const float4*)&zbuf[w][b_loc][oc + i];
            s0 += v.x; s1 += v.y; s2 += v.z; s3 += v.w;
        }
        zz[i] = s0; zz[i + 1] = s1; zz[i + 2] = s2; zz[i + 3] = s3;
    }

    const int b = rbase + b_loc;
    const size_t xzoff = ((size_t)t_rel * B_ + b) * N4H + cbase + oc;
    float4 xa = *(const float4*)(xz + xzoff);
    float4 xb = *(const float4*)(xz + xzoff + 4);
    zz[0] += xa.x; zz[1] += xa.y; zz[2] += xa.z; zz[3] += xa.w;
    zz[4] += xb.x; zz[5] += xb.y; zz[6] += xb.z; zz[7] += xb.w;

    const int j0 = cg * 16 + (tid & 7) * 2;   // first of 2 cells
    float2 cold = *(const float2*)&cst[b * H_ + j0];
    float coldv[2] = {cold.x, cold.y};

    float cnew[2];
    unsigned short hh[2], hl[2];
    #pragma unroll
    for (int j = 0; j < 2; ++j) {
        float zg = zz[4 * j + 0];
        float zi = zz[4 * j + 1];
        float zf = zz[4 * j + 2];
        float zo = zz[4 * j + 3];
        float g  = tanhf(zg);
        float ig = 1.f / (1.f + expf(-zi));
        float fg = 1.f / (1.f + expf(-zf));
        float og = 1.f / (1.f + expf(-zo));
        float cn = g * ig + coldv[j] * fg;
        float hn = tanhf(cn) * og;
        cnew[j] = cn;
        unsigned short h16 = f2bf(hn);
        hh[j] = h16;
        hl[j] = f2bf(hn - bf2f(h16));
    }
    *(float2*)&cst[b * H_ + j0] = make_float2(cnew[0], cnew[1]);
    *(ushort2*)&hout_hi[b * H_ + j0] = make_ushort2(hh[0], hh[1]);
    *(ushort2*)&hout_lo[b * H_ + j0] = make_ushort2(hl[0], hl[1]);
}

// ---------------------------------------------------------------------------
// Final projection + softmax: one block per batch row, 128 threads.
// ---------------------------------------------------------------------------
__global__ __launch_bounds__(128) void final_proj(
    const unsigned short* __restrict__ hhi, const unsigned short* __restrict__ hlo,
    const float* __restrict__ Why, const float* __restrict__ bhy,
    float* __restrict__ out)
{
    __shared__ float hsh[H_];
    __shared__ float red[O_];
    const int b = blockIdx.x, tid = threadIdx.x;

    for (int k = tid; k < H_; k += O_)
        hsh[k] = bf2f(hhi[(size_t)b * H_ + k]) + bf2f(hlo[(size_t)b * H_ + k]);
    __syncthreads();

    float s = bhy[tid];
    const float* w = Why + (size_t)tid * H_;
    #pragma unroll 4
    for (int k = 0; k < H_; k += 4) {
        float4 wv = *(const float4*)(w + k);
        s += hsh[k] * wv.x + hsh[k + 1] * wv.y + hsh[k + 2] * wv.z + hsh[k + 3] * wv.w;
    }

    red[tid] = s; __syncthreads();
    for (int off = 64; off > 0; off >>= 1) {
        if (tid < off) red[tid] = fmaxf(red[tid], red[tid + off]);
        __syncthreads();
    }
    float mx = red[0]; __syncthreads();
    float e = expf(s - mx);
    red[tid] = e; __syncthreads();
    for (int off = 64; off > 0; off >>= 1) {
        if (tid < off) red[tid] += red[tid + off];
        __syncthreads();
    }
    out[(size_t)b * O_ + tid] = e / red[0];
}

// ---------------------------------------------------------------------------
extern "C" void kernel_launch(void* const* d_in, const int* in_sizes, int n_in,
                              void* d_out, int out_size, void* d_ws, size_t ws_size,
                              hipStream_t stream)
{
    const float* x   = (const float*)d_in[0];
    const float* Wgx = (const float*)d_in[1];
    const float* bgx = (const float*)d_in[2];
    const float* Wgh = (const float*)d_in[3];
    const float* Wix = (const float*)d_in[4];
    const float* bix = (const float*)d_in[5];
    const float* Wih = (const float*)d_in[6];
    const float* Wfx = (const float*)d_in[7];
    const float* bfx = (const float*)d_in[8];
    const float* Wfh = (const float*)d_in[9];
    const float* Wox = (const float*)d_in[10];
    const float* box = (const float*)d_in[11];
    const float* Woh = (const float*)d_in[12];
    const float* Why = (const float*)d_in[13];
    const float* bhy = (const float*)d_in[14];

    // workspace layout (fixed ~23 MB + xz chunk buffer)
    unsigned short* Whhi = (unsigned short*)d_ws;                 // 4096*1024
    unsigned short* Whlo = Whhi + (size_t)N4H * H_;
    unsigned short* WXhi = Whlo + (size_t)N4H * H_;               // 4096*256
    unsigned short* WXlo = WXhi + (size_t)N4H * D_;
    float*          bP   = (float*)(WXlo + (size_t)N4H * D_);
    unsigned short* hA_hi = (unsigned short*)(bP + N4H);
    unsigned short* hA_lo = hA_hi + (size_t)B_ * H_;
    float*          cst   = (float*)(hA_lo + (size_t)B_ * H_);
    unsigned short* hB_hi = (unsigned short*)(cst + (size_t)B_ * H_);
    unsigned short* hB_lo = hB_hi + (size_t)B_ * H_;
    float*          xz    = (float*)(hB_lo + (size_t)B_ * H_);

    const size_t fixed_bytes = (size_t)((char*)xz - (char*)d_ws);
    const size_t per_t = (size_t)B_ * N4H * sizeof(float);        // 4 MB per time step
    int Tc = 1;
    if (ws_size > fixed_bytes) {
        size_t fit = (ws_size - fixed_bytes) / per_t;
        Tc = (fit > 64) ? 64 : (fit < 1 ? 1 : (int)fit);
    }

    // zero h ping buffer and c (contiguous: hA_hi, hA_lo, cst)
    hipMemsetAsync(hA_hi, 0, (size_t)B_ * H_ * 8, stream);

    const int totalW = N4H * (H_ + D_);
    pack_weights<<<(totalW + 255) / 256, 256, 0, stream>>>(
        Wgx, bgx, Wgh, Wix, bix, Wih, Wfx, bfx, Wfh, Wox, box, Woh,
        Whhi, Whlo, WXhi, WXlo, bP);

    for (int t0 = 0; t0 < T_; t0 += Tc) {
        const int tc = (T_ - t0 < Tc) ? (T_ - t0) : Tc;
        xz_gemm<<<dim3(32, 2 * tc), 256, 0, stream>>>(x, WXhi, WXlo, bP, xz, t0);
        for (int t = t0; t < t0 + tc; ++t) {
            const unsigned short* ih = (t & 1) ? hB_hi : hA_hi;
            const unsigned short* il = (t & 1) ? hB_lo : hA_lo;
            unsigned short* oh = (t & 1) ? hA_hi : hB_hi;
            unsigned short* ol = (t & 1) ? hA_lo : hB_lo;
            lstm_step<<<256, 512, 0, stream>>>(
                Whhi, Whlo, ih, il, oh, ol, cst, xz, t - t0);
        }
    }

    // T=512 even: last step (t=511, odd) wrote the A buffers
    final_proj<<<B_, 128, 0, stream>>>(hA_hi, hA_lo, Why, bhy, (float*)d_out);
}